// Round 8
// baseline (21.775 us; speedup 1.0000x reference)
//
#include <hip/hip_runtime.h>

#define DIM   1024
#define SEQ_  2048
#define NBAT  4

typedef float nativef4 __attribute__((ext_vector_type(4)));

// One 64-lane wave per row, 4 rows per 256-thread block, NT stores.
// Register economy: only the 4 embedding gathers (the true L2/L3-latency
// loads) are prefetched; book_table reads (16KB, L1-resident) are issued
// in-loop. __launch_bounds__(256,8) pins VGPR<=64 for 8 waves/SIMD so the
// full grid (exactly 32 waves/CU) is co-resident during the gather storm.
__global__ __launch_bounds__(256, 8) void verse_embed_ln_kernel(
    const int*   __restrict__ token_ids,    // [B,S]
    const int*   __restrict__ verse_pos,    // [B,S]
    const int*   __restrict__ book_types,   // [B,S]
    const float* __restrict__ emb_table,    // [VOCAB,D]
    const float* __restrict__ book_table,   // [4,D]
    const float* __restrict__ gamma,        // [D]
    const float* __restrict__ beta,         // [D]
    float*       __restrict__ out)          // [B,S,D]
{
    const int wid  = threadIdx.x >> 6;
    const int lane = threadIdx.x & 63;
    const int row  = (blockIdx.x << 2) + wid;   // 0 .. B*S-1
    const int s    = row & (SEQ_ - 1);

    // wave-uniform per-row metadata (scalarized)
    const int tok   = token_ids[row];
    const int bt    = book_types[row];
    const int v     = verse_pos[row];
    const int vprev = (s == 0) ? -1 : verse_pos[row - 1];
    // verse_positions sorted per row (zeros first) => run-start test is local
    const float w = (v != 0 && v != vprev) ? 1.2f : 1.0f;

    const float4* __restrict__ erow = reinterpret_cast<const float4*>(emb_table)  + (size_t)tok * 256;
    const float4* __restrict__ brow = reinterpret_cast<const float4*>(book_table) + (size_t)bt  * 256;

    // prefetch only the high-latency gathers
    float4 e[4];
    #pragma unroll
    for (int c = 0; c < 4; ++c) e[c] = erow[c * 64 + lane];

    // frequencies: f(d)=10000^(-d/1024); f(d+2)=f(d)*K2; f(d+256)=f(d)*0.1
    const float C2 = -13.287712379549449f / 1024.0f;   // -log2(10000)/D
    const float K2 = 0.9821718931198913f;              // 10000^(-1/512)
    const int   dl = lane << 2;
    const float sf = (float)s;
    float fb = exp2f(C2 * (float)dl);
    const float SQD = 32.0f;

    float4 x[4];
    float sum = 0.0f, sq = 0.0f;
    #pragma unroll
    for (int c = 0; c < 4; ++c) {
        const float4 bk = brow[c * 64 + lane];   // L1-resident, short latency
        const float a0 = sf * fb;
        const float a1 = sf * (fb * K2);
        const float sn0 = __sinf(a0), cs0 = __cosf(a0);
        const float sn1 = __sinf(a1), cs1 = __cosf(a1);
        fb *= 0.1f;
        x[c].x = e[c].x * SQD + sn0 * w + bk.x;
        x[c].y = e[c].y * SQD + cs0 * w + bk.y;
        x[c].z = e[c].z * SQD + sn1 * w + bk.z;
        x[c].w = e[c].w * SQD + cs1 * w + bk.w;
        sum += (x[c].x + x[c].y) + (x[c].z + x[c].w);
        sq  += (x[c].x * x[c].x + x[c].y * x[c].y) + (x[c].z * x[c].z + x[c].w * x[c].w);
    }

    #pragma unroll
    for (int off = 32; off >= 1; off >>= 1) {
        sum += __shfl_xor(sum, off, 64);
        sq  += __shfl_xor(sq,  off, 64);
    }

    const float mean = sum * (1.0f / (float)DIM);
    const float var  = sq * (1.0f / (float)DIM) - mean * mean;
    const float rstd = rsqrtf(var + 1e-5f);

    const float4* __restrict__ g4 = reinterpret_cast<const float4*>(gamma);
    const float4* __restrict__ b4 = reinterpret_cast<const float4*>(beta);
    nativef4* __restrict__ orow = reinterpret_cast<nativef4*>(out) + (size_t)row * 256;
    #pragma unroll
    for (int c = 0; c < 4; ++c) {
        const float4 g  = g4[c * 64 + lane];     // L1-resident
        const float4 bb = b4[c * 64 + lane];     // L1-resident
        nativef4 o;
        o.x = (x[c].x - mean) * rstd * g.x + bb.x;
        o.y = (x[c].y - mean) * rstd * g.y + bb.y;
        o.z = (x[c].z - mean) * rstd * g.z + bb.z;
        o.w = (x[c].w - mean) * rstd * g.w + bb.w;
        __builtin_nontemporal_store(o, &orow[c * 64 + lane]);
    }
}

extern "C" void kernel_launch(void* const* d_in, const int* in_sizes, int n_in,
                              void* d_out, int out_size, void* d_ws, size_t ws_size,
                              hipStream_t stream) {
    const int*   token_ids  = (const int*)d_in[0];
    const int*   verse_pos  = (const int*)d_in[1];
    const int*   book_types = (const int*)d_in[2];
    const float* emb_table  = (const float*)d_in[3];
    const float* book_table = (const float*)d_in[4];
    const float* ln_gamma   = (const float*)d_in[5];
    const float* ln_beta    = (const float*)d_in[6];
    float* out = (float*)d_out;

    dim3 grid((NBAT * SEQ_) / 4);   // one wave per row, 4 rows per 256-thread block
    dim3 block(256);
    verse_embed_ln_kernel<<<grid, block, 0, stream>>>(
        token_ids, verse_pos, book_types, emb_table, book_table,
        ln_gamma, ln_beta, out);
}

// Round 9
// 14.762 us; speedup vs baseline: 1.4750x; 1.4750x over previous
//
#include <hip/hip_runtime.h>

#define DIM   1024
#define SEQ_  2048
#define NBAT  4

typedef float nativef4 __attribute__((ext_vector_type(4)));

// One 64-lane wave per row, 4 rows per 256-thread block, NT stores.
// vs R7: book_table reads moved in-loop (L1-resident, short latency) to cut
// peak live VGPRs by 16, and a MILD bound (256,6) -> VGPR cap 84, targeting
// 6 waves/SIMD without spills (R8's (256,8)/cap-64 spilled and regressed).
__global__ __launch_bounds__(256, 6) void verse_embed_ln_kernel(
    const int*   __restrict__ token_ids,    // [B,S]
    const int*   __restrict__ verse_pos,    // [B,S]
    const int*   __restrict__ book_types,   // [B,S]
    const float* __restrict__ emb_table,    // [VOCAB,D]
    const float* __restrict__ book_table,   // [4,D]
    const float* __restrict__ gamma,        // [D]
    const float* __restrict__ beta,         // [D]
    float*       __restrict__ out)          // [B,S,D]
{
    const int wid  = threadIdx.x >> 6;
    const int lane = threadIdx.x & 63;
    const int row  = (blockIdx.x << 2) + wid;   // 0 .. B*S-1
    const int s    = row & (SEQ_ - 1);

    // wave-uniform per-row metadata (scalarized)
    const int tok   = token_ids[row];
    const int bt    = book_types[row];
    const int v     = verse_pos[row];
    const int vprev = (s == 0) ? -1 : verse_pos[row - 1];
    // verse_positions sorted per row (zeros first) => run-start test is local
    const float w = (v != 0 && v != vprev) ? 1.2f : 1.0f;

    const float4* __restrict__ erow = reinterpret_cast<const float4*>(emb_table)  + (size_t)tok * 256;
    const float4* __restrict__ brow = reinterpret_cast<const float4*>(book_table) + (size_t)bt  * 256;

    // prefetch only the high-latency gathers
    float4 e[4];
    #pragma unroll
    for (int c = 0; c < 4; ++c) e[c] = erow[c * 64 + lane];

    // frequencies: f(d)=10000^(-d/1024); f(d+2)=f(d)*K2; f(d+256)=f(d)*0.1
    const float C2 = -13.287712379549449f / 1024.0f;   // -log2(10000)/D
    const float K2 = 0.9821718931198913f;              // 10000^(-1/512)
    const int   dl = lane << 2;
    const float sf = (float)s;
    float fb = exp2f(C2 * (float)dl);
    const float SQD = 32.0f;

    float4 x[4];
    float sum = 0.0f, sq = 0.0f;
    #pragma unroll
    for (int c = 0; c < 4; ++c) {
        const float4 bk = brow[c * 64 + lane];   // L1-resident, short latency
        const float a0 = sf * fb;
        const float a1 = sf * (fb * K2);
        const float sn0 = __sinf(a0), cs0 = __cosf(a0);
        const float sn1 = __sinf(a1), cs1 = __cosf(a1);
        fb *= 0.1f;
        x[c].x = e[c].x * SQD + sn0 * w + bk.x;
        x[c].y = e[c].y * SQD + cs0 * w + bk.y;
        x[c].z = e[c].z * SQD + sn1 * w + bk.z;
        x[c].w = e[c].w * SQD + cs1 * w + bk.w;
        sum += (x[c].x + x[c].y) + (x[c].z + x[c].w);
        sq  += (x[c].x * x[c].x + x[c].y * x[c].y) + (x[c].z * x[c].z + x[c].w * x[c].w);
    }

    #pragma unroll
    for (int off = 32; off >= 1; off >>= 1) {
        sum += __shfl_xor(sum, off, 64);
        sq  += __shfl_xor(sq,  off, 64);
    }

    const float mean = sum * (1.0f / (float)DIM);
    const float var  = sq * (1.0f / (float)DIM) - mean * mean;
    const float rstd = rsqrtf(var + 1e-5f);

    const float4* __restrict__ g4 = reinterpret_cast<const float4*>(gamma);
    const float4* __restrict__ b4 = reinterpret_cast<const float4*>(beta);
    nativef4* __restrict__ orow = reinterpret_cast<nativef4*>(out) + (size_t)row * 256;
    #pragma unroll
    for (int c = 0; c < 4; ++c) {
        const float4 g  = g4[c * 64 + lane];     // L1-resident
        const float4 bb = b4[c * 64 + lane];     // L1-resident
        nativef4 o;
        o.x = (x[c].x - mean) * rstd * g.x + bb.x;
        o.y = (x[c].y - mean) * rstd * g.y + bb.y;
        o.z = (x[c].z - mean) * rstd * g.z + bb.z;
        o.w = (x[c].w - mean) * rstd * g.w + bb.w;
        __builtin_nontemporal_store(o, &orow[c * 64 + lane]);
    }
}

extern "C" void kernel_launch(void* const* d_in, const int* in_sizes, int n_in,
                              void* d_out, int out_size, void* d_ws, size_t ws_size,
                              hipStream_t stream) {
    const int*   token_ids  = (const int*)d_in[0];
    const int*   verse_pos  = (const int*)d_in[1];
    const int*   book_types = (const int*)d_in[2];
    const float* emb_table  = (const float*)d_in[3];
    const float* book_table = (const float*)d_in[4];
    const float* ln_gamma   = (const float*)d_in[5];
    const float* ln_beta    = (const float*)d_in[6];
    float* out = (float*)d_out;

    dim3 grid((NBAT * SEQ_) / 4);   // one wave per row, 4 rows per 256-thread block
    dim3 block(256);
    verse_embed_ln_kernel<<<grid, block, 0, stream>>>(
        token_ids, verse_pos, book_types, emb_table, book_table,
        ln_gamma, ln_beta, out);
}